// Round 2
// baseline (739.996 us; speedup 1.0000x reference)
//
#include <hip/hip_runtime.h>

// Shapes (hardcoded for this problem instance):
//   x: (2, 384, 256, 256) fp32, w_qkv: (1152, 384) fp32, w_proj: (384, 384) fp32
//   out: (2, 384, 256, 256) fp32.  WS=8, NH=8, HD=48.  256%8==0 -> no reflect pad.
// pix' = b*65536 + win*64 + t  (window-ordered pixel index, win = wy*32+wx, t = ty*8+tx)

#define NPIX 131072   // 2*256*256
#define KDIM 384
#define SCALE 0.14433756729740643f  // 48^-0.5

typedef __attribute__((ext_vector_type(8))) short bf16x8;   // 8 bf16 in 4 VGPRs
typedef __attribute__((ext_vector_type(4))) float floatx4;

__device__ __forceinline__ unsigned short f2b(float f) {
  union { float f; unsigned u; } v; v.f = f;
  return (unsigned short)((v.u + 0x7FFFu + ((v.u >> 16) & 1u)) >> 16);  // RNE
}

__device__ __forceinline__ floatx4 mfma_bf16(bf16x8 a, bf16x8 b, floatx4 c) {
  return __builtin_amdgcn_mfma_f32_16x16x32_bf16(a, b, c, 0, 0, 0);
}

// async 16B global -> LDS (wave-uniform LDS base + lane*16)
__device__ __forceinline__ void async16(const void* g, void* lds) {
  __builtin_amdgcn_global_load_lds(
      (const __attribute__((address_space(1))) unsigned int*)g,
      (__attribute__((address_space(3))) unsigned int*)lds, 16, 0, 0);
}

// ---------------------------------------------------------------- weights cast
__global__ __launch_bounds__(256) void wcvt(const float* __restrict__ wq,
                                            const float* __restrict__ wp,
                                            unsigned short* __restrict__ wqb,
                                            unsigned short* __restrict__ wpb) {
  int i = blockIdx.x * 256 + threadIdx.x;
  if (i < 1152 * 384) wqb[i] = f2b(wq[i]);
  if (i < 384 * 384)  wpb[i] = f2b(wp[i]);
}

// ------------------------------------------- x (b,c,raster) fp32 -> xT[pix'][c] bf16
// block: (b, wy, wxg of 4 windows, cg of 32 channels); 2*32*8*12 = 6144 blocks
// float4 global reads (8 issues/thread instead of 32 scalar).
__global__ __launch_bounds__(256) void transpose_cast(const float* __restrict__ x,
                                                      unsigned short* __restrict__ xT) {
  __shared__ unsigned short sT[256 * 40];  // [pixloc][c], stride 40 (16B aligned rows)
  int id = blockIdx.x;
  int cg = id % 12; id /= 12;
  int wxg = id % 8; id /= 8;
  int wy = id % 32; id /= 32;
  int b = id;
  int tid = threadIdx.x;
  const float* xb = x + ((size_t)(b * 384 + cg * 32)) * 65536 + (size_t)(wy * 8) * 256 + wxg * 32;
#pragma unroll
  for (int it = 0; it < 8; ++it) {
    int e = it * 256 + tid;          // 0..2047: (c, y, x4)
    int c = e >> 6, rem = e & 63, y = rem >> 3, x4 = rem & 7;
    float4 v = *(const float4*)&xb[(size_t)c * 65536 + y * 256 + x4 * 4];
    int xx = x4 * 4;
    int p0 = (xx >> 3) * 64 + y * 8 + (xx & 7);   // +i for i=0..3 stays in-window (no carry)
    unsigned short* dst = &sT[p0 * 40 + c];
    dst[0]   = f2b(v.x);
    dst[40]  = f2b(v.y);
    dst[80]  = f2b(v.z);
    dst[120] = f2b(v.w);
  }
  __syncthreads();
  int wl = tid >> 6, t = tid & 63;
  size_t pix = (size_t)b * 65536 + (size_t)(wy * 32 + wxg * 4 + wl) * 64 + t;
  unsigned short* dst = xT + pix * 384 + cg * 32;
  const unsigned short* src = &sT[tid * 40];
#pragma unroll
  for (int q = 0; q < 4; ++q)
    *(uint4*)(dst + q * 8) = *(const uint4*)(src + q * 8);
}

// ---------------------------------------------------------------- bf16 MFMA GEMM
// C[m][n] = sum_k A[m][k] * B[n][k]; A [M][K] bf16, B [N][K] bf16, K%64==0.
// MODE 0: store bf16 C[m*N+n]  (qkv).  MODE 1: scatter fp32 to (b,o,raster) (out).
// 128x128 tile, BK=64, 4 waves each 64x64 (4x4 MFMA tiles), XOR-swizzled LDS.
// 1D grid = (N/128)*(M/128); XCD-chunked swizzle with M-tile fastest so the 9 (or 3)
// blocks sharing a B-tile are consecutive on the same XCD (B read once from HBM).
// Staging is global_load_lds width=16 with the XOR swizzle applied to the SOURCE
// address (LDS dest stays linear). Epilogue stages C in LDS (reusing As/Bs) and
// writes coalesced >=64B segments.
template <int MODE>
__global__ __launch_bounds__(256, 2) void gemm_bt(const unsigned short* __restrict__ A,
                                                  const unsigned short* __restrict__ B,
                                                  void* __restrict__ Cout,
                                                  int M, int N, int K) {
  __shared__ uint4 smem4[2176];  // 34816 B: k-loop uses [0,32768) as As|Bs; epilogue reuses all
  unsigned short* As = (unsigned short*)smem4;            // 128*64 bf16, 16 KB
  unsigned short* Bs = (unsigned short*)smem4 + 128 * 64; // 16 KB
  const int tid = threadIdx.x;
  const int MT = M >> 7;  // 9 (qkv) or 3 (proj)

  // XCD-chunked bijective swizzle (gridDim.x divisible by 8; per-XCD N-range exact)
  const int per = gridDim.x >> 3;
  const int vbid = (blockIdx.x & 7) * per + (blockIdx.x >> 3);
  const int Mbase = (vbid % MT) * 128;
  const int Nbase = (vbid / MT) * 128;

  const int wave = tid >> 6, lane = tid & 63;
  const int wm = wave >> 1, wn = wave & 1;
  const int l16 = lane & 15, quad = lane >> 4;
  const int Kv = K >> 3;        // row stride in uint4
  const int kTiles = K >> 6;

  // staging geometry: lane -> row lr (0..7 within wave group), source k-chunk
  // pre-swizzled so that linear LDS dest chunk (m,lk) holds global chunk lk^(m&7)
  const int lr = lane >> 3;
  const int kbs = (lane & 7) ^ lr;           // source 16B chunk within 64-k tile
  const int mrow = wave * 8 + lr;            // 0..31

  floatx4 acc[4][4];
#pragma unroll
  for (int mt = 0; mt < 4; ++mt)
#pragma unroll
    for (int nt = 0; nt < 4; ++nt) acc[mt][nt] = 0.f;

  const uint4* Ag = (const uint4*)(A + (size_t)Mbase * K);
  const uint4* Bg = (const uint4*)(B + (size_t)Nbase * K);

  for (int kt = 0; kt < kTiles; ++kt) {
    __syncthreads();  // previous iteration's LDS reads complete
#pragma unroll
    for (int j = 0; j < 4; ++j) {
      int m = j * 32 + mrow;
      async16(Ag + (size_t)m * Kv + kt * 8 + kbs, (char*)As + j * 4096 + wave * 1024);
      async16(Bg + (size_t)m * Kv + kt * 8 + kbs, (char*)Bs + j * 4096 + wave * 1024);
    }
    __syncthreads();  // compiler drains vmcnt(0) before barrier -> LDS visible
#pragma unroll
    for (int s = 0; s < 2; ++s) {
      bf16x8 af[4], bfr[4];
#pragma unroll
      for (int mt = 0; mt < 4; ++mt) {
        int m = wm * 64 + mt * 16 + l16;
        int kk = (s * 4 + quad) ^ (m & 7);
        af[mt] = *(const bf16x8*)&As[(m * 8 + kk) * 8];
      }
#pragma unroll
      for (int nt = 0; nt < 4; ++nt) {
        int n = wn * 64 + nt * 16 + l16;
        int kk = (s * 4 + quad) ^ (n & 7);
        bfr[nt] = *(const bf16x8*)&Bs[(n * 8 + kk) * 8];
      }
#pragma unroll
      for (int mt = 0; mt < 4; ++mt)
#pragma unroll
        for (int nt = 0; nt < 4; ++nt)
          acc[mt][nt] = mfma_bf16(af[mt], bfr[nt], acc[mt][nt]);
    }
  }

  // ---------------- epilogue: LDS-staged coalesced stores
  // C/D layout: col = l16 (n), row = quad*4 + reg (m)
  if (MODE == 0) {
    unsigned short* Cs = (unsigned short*)smem4;  // [128][136] bf16 (pad breaks bank stride)
    __syncthreads();  // done reading As/Bs
#pragma unroll
    for (int mt = 0; mt < 4; ++mt)
#pragma unroll
      for (int nt = 0; nt < 4; ++nt)
#pragma unroll
        for (int r = 0; r < 4; ++r) {
          int lm = wm * 64 + mt * 16 + quad * 4 + r;
          int ln = wn * 64 + nt * 16 + l16;
          Cs[lm * 136 + ln] = f2b(acc[mt][nt][r]);
        }
    __syncthreads();
    // 128 rows x 256B contiguous; wave covers 4 rows x 256B per iteration
#pragma unroll
    for (int it = 0; it < 8; ++it) {
      int slot = it * 256 + tid;
      int row = slot >> 4, ch = slot & 15;
      *(uint4*)((unsigned short*)Cout + (size_t)(Mbase + row) * N + Nbase + ch * 8) =
          *(const uint4*)&Cs[row * 136 + ch * 8];
    }
  } else {
    // fp32 scatter to (b, m, hh, ww). Tile = 2 adjacent windows -> 16 contiguous ww
    // per (m, hh): 64B segments. Two passes of 64 rows (32 KB fp32 stage each).
    float* Fs = (float*)smem4;  // [64][136] fp32
    const int b = Nbase >> 16;
    const int win0 = (Nbase & 65535) >> 6;  // even; win0,win0+1 share the wy row
    const int hh0 = (win0 >> 5) * 8;
    const int ww0 = (win0 & 31) * 8;
#pragma unroll
    for (int p = 0; p < 2; ++p) {
      __syncthreads();  // protect As/Bs reads (p=0) / previous pass reads (p=1)
#pragma unroll
      for (int mth = 0; mth < 2; ++mth) {
        int mt = p * 2 + mth;
#pragma unroll
        for (int nt = 0; nt < 4; ++nt)
#pragma unroll
          for (int r = 0; r < 4; ++r) {
            int lrow = wm * 32 + mth * 16 + quad * 4 + r;  // 0..63
            int ln = wn * 64 + nt * 16 + l16;
            Fs[lrow * 136 + ln] = acc[mt][nt][r];
          }
      }
      __syncthreads();
      // 512 segments (lrow, ty) of 64B; 4 lanes per segment write float4 each
#pragma unroll
      for (int it = 0; it < 8; ++it) {
        int slot = it * 256 + tid;
        int q4 = slot & 3;        // 16B quarter within the 64B segment
        int seg = slot >> 2;      // 0..511
        int ty = seg & 7, lrow = seg >> 3;
        int m = Mbase + (lrow >> 5) * 64 + p * 32 + (lrow & 31);
        // cols ty*8..+7 (win0) and 64+ty*8..+7 (win1) -> ww0..ww0+15
        int base_col = (q4 >> 1) * 64 + ty * 8 + (q4 & 1) * 4;
        float4 v = *(const float4*)&Fs[lrow * 136 + base_col];
        float* dst = (float*)Cout + ((size_t)(b * 384 + m)) * 65536 +
                     (size_t)(hh0 + ty) * 256 + ww0 + q4 * 4;
        *(float4*)dst = v;
      }
    }
  }
}

// ---------------------------------------------------------------- window attention
// block = (window, head); 256 threads (4 waves, wave w owns q-rows [16w,16w+16))
// Loads vectorized: q,k via uint2 (8B/lane, 4 px) + transposed in-register unpack;
// v via uint4 rows. 6+1.5 wide global issues/thread vs 25 scalar before.
__global__ __launch_bounds__(256, 2) void attn_kernel(const unsigned short* __restrict__ qkv,
                                                      unsigned short* __restrict__ ao) {
  __shared__ unsigned short sQ[64 * 72];  // [t][d], d padded 48->64, stride 72
  __shared__ unsigned short sK[64 * 72];  // [u][d]
  __shared__ unsigned short sV[48 * 72];  // [d][u], stride 72
  __shared__ unsigned short sP[64 * 72];  // [t][u]
  const int wh = blockIdx.x;
  const int wing = wh >> 3, h = wh & 7;
  const int wb = wing * 64;  // pix' base
  const int tid = threadIdx.x;

  {
    // zero-pad d=48..63 (chunks 6,7) of sQ,sK
    if (tid < 128) {
      int t = tid >> 1, ch = tid & 1;
      const uint4 z = {0u, 0u, 0u, 0u};
      *(uint4*)&sQ[t * 72 + 48 + ch * 8] = z;
      *(uint4*)&sK[t * 72 + 48 + ch * 8] = z;
    }
    // q,k: 48 d-rows x 16 groups of 4 consecutive px; uint2 = 4 bf16 along t
#pragma unroll
    for (int j = 0; j < 3; ++j) {
      int task = j * 256 + tid;     // 0..767 = 48*16
      int d = task >> 4, g = task & 15;
      uint2 vq = *(const uint2*)&qkv[(size_t)(h * 48 + d) * NPIX + wb + g * 4];
      uint2 vk = *(const uint2*)&qkv[(size_t)(384 + h * 48 + d) * NPIX + wb + g * 4];
      unsigned short* q0 = &sQ[(g * 4) * 72 + d];
      unsigned short* k0 = &sK[(g * 4) * 72 + d];
      q0[0]   = (unsigned short)(vq.x);
      q0[72]  = (unsigned short)(vq.x >> 16);
      q0[144] = (unsigned short)(vq.y);
      q0[216] = (unsigned short)(vq.y >> 16);
      k0[0]   = (unsigned short)(vk.x);
      k0[72]  = (unsigned short)(vk.x >> 16);
      k0[144] = (unsigned short)(vk.y);
      k0[216] = (unsigned short)(vk.y >> 16);
    }
    // v direct rows [d][u] via uint4
    for (int idx = tid; idx < 384; idx += 256) {
      int d = idx >> 3, c8 = idx & 7;
      *(uint4*)&sV[d * 72 + c8 * 8] =
          *(const uint4*)&qkv[(size_t)(768 + h * 48 + d) * NPIX + wb + c8 * 8];
    }
  }
  __syncthreads();

  const int wave = tid >> 6, lane = tid & 63;
  const int l16 = lane & 15, quad = lane >> 4;
  const int tb = wave * 16;

  // S = Q K^T (K-dim = d, padded to 64)
  floatx4 sacc[4];
#pragma unroll
  for (int nt = 0; nt < 4; ++nt) sacc[nt] = 0.f;
#pragma unroll
  for (int s = 0; s < 2; ++s) {
    bf16x8 aq = *(const bf16x8*)&sQ[(tb + l16) * 72 + s * 32 + quad * 8];
#pragma unroll
    for (int nt = 0; nt < 4; ++nt) {
      bf16x8 bk = *(const bf16x8*)&sK[(nt * 16 + l16) * 72 + s * 32 + quad * 8];
      sacc[nt] = mfma_bf16(aq, bk, sacc[nt]);
    }
  }
  // softmax over u (rows live on 16 lanes sharing quad, x 4 col-tiles)
#pragma unroll
  for (int r = 0; r < 4; ++r) {
    float v0 = sacc[0][r] * SCALE, v1 = sacc[1][r] * SCALE;
    float v2 = sacc[2][r] * SCALE, v3 = sacc[3][r] * SCALE;
    float mx = fmaxf(fmaxf(v0, v1), fmaxf(v2, v3));
    mx = fmaxf(mx, __shfl_xor(mx, 1));
    mx = fmaxf(mx, __shfl_xor(mx, 2));
    mx = fmaxf(mx, __shfl_xor(mx, 4));
    mx = fmaxf(mx, __shfl_xor(mx, 8));
    float p0 = __expf(v0 - mx), p1 = __expf(v1 - mx);
    float p2 = __expf(v2 - mx), p3 = __expf(v3 - mx);
    float sum = p0 + p1 + p2 + p3;
    sum += __shfl_xor(sum, 1);
    sum += __shfl_xor(sum, 2);
    sum += __shfl_xor(sum, 4);
    sum += __shfl_xor(sum, 8);
    float inv = 1.f / sum;
    int t = tb + quad * 4 + r;
    sP[t * 72 + 0 * 16 + l16] = f2b(p0 * inv);
    sP[t * 72 + 1 * 16 + l16] = f2b(p1 * inv);
    sP[t * 72 + 2 * 16 + l16] = f2b(p2 * inv);
    sP[t * 72 + 3 * 16 + l16] = f2b(p3 * inv);
  }
  __syncthreads();

  // O = P V  (K-dim = u = 64, N-dim = d = 48)
  floatx4 oacc[3];
#pragma unroll
  for (int nt = 0; nt < 3; ++nt) oacc[nt] = 0.f;
#pragma unroll
  for (int s = 0; s < 2; ++s) {
    bf16x8 ap = *(const bf16x8*)&sP[(tb + l16) * 72 + s * 32 + quad * 8];
#pragma unroll
    for (int nt = 0; nt < 3; ++nt) {
      bf16x8 bv = *(const bf16x8*)&sV[(nt * 16 + l16) * 72 + s * 32 + quad * 8];
      oacc[nt] = mfma_bf16(ap, bv, oacc[nt]);
    }
  }
#pragma unroll
  for (int nt = 0; nt < 3; ++nt) {
#pragma unroll
    for (int r = 0; r < 4; ++r) {
      int t = tb + quad * 4 + r;
      int d = nt * 16 + l16;
      ao[((size_t)(wb + t)) * 384 + h * 48 + d] = f2b(oacc[nt][r]);
    }
  }
}

// ---------------------------------------------------------------- launch
extern "C" void kernel_launch(void* const* d_in, const int* in_sizes, int n_in,
                              void* d_out, int out_size, void* d_ws, size_t ws_size,
                              hipStream_t stream) {
  const float* x  = (const float*)d_in[0];
  const float* wq = (const float*)d_in[1];
  const float* wp = (const float*)d_in[2];
  float* out = (float*)d_out;

  char* ws = (char*)d_ws;
  // workspace layout (bytes): needs ~504.5 MB
  unsigned short* xT  = (unsigned short*)(ws);                          // 100,663,296
  unsigned short* qkv = (unsigned short*)(ws + 100663296ull);           // 301,989,888
  unsigned short* ao  = (unsigned short*)(ws + 402653184ull);           // 100,663,296
  unsigned short* wqb = (unsigned short*)(ws + 503316480ull);           //     884,736
  unsigned short* wpb = (unsigned short*)(ws + 504201216ull);           //     294,912

  wcvt<<<1728, 256, 0, stream>>>(wq, wp, wqb, wpb);
  transpose_cast<<<6144, 256, 0, stream>>>(x, xT);
  gemm_bt<0><<<9216, 256, 0, stream>>>(wqb, xT, qkv, 1152, NPIX, KDIM);
  attn_kernel<<<16384, 256, 0, stream>>>(qkv, ao);
  gemm_bt<1><<<3072, 256, 0, stream>>>(wpb, ao, out, 384, NPIX, KDIM);
}

// Round 4
// 711.943 us; speedup vs baseline: 1.0394x; 1.0394x over previous
//
#include <hip/hip_runtime.h>

// Shapes (hardcoded): x (2,384,256,256) fp32, w_qkv (1152,384), w_proj (384,384).
// out (2,384,256,256) fp32.  WS=8, NH=8, HD=48.  256%8==0 -> no reflect pad.
// wing = b*1024 + wy*32 + wx  (global window id, 2048 total), t = ty*8+tx.
// qkv2 layout: [wing][c=1152][t=64] bf16 (per-window contiguous 147 KB slice).

#define NPIX 131072   // 2*256*256
#define KDIM 384
#define SCALE 0.14433756729740643f  // 48^-0.5

typedef __attribute__((ext_vector_type(8))) short bf16x8;   // 8 bf16 in 4 VGPRs
typedef __attribute__((ext_vector_type(4))) float floatx4;

__device__ __forceinline__ unsigned short f2b(float f) {
  union { float f; unsigned u; } v; v.f = f;
  return (unsigned short)((v.u + 0x7FFFu + ((v.u >> 16) & 1u)) >> 16);  // RNE
}

__device__ __forceinline__ floatx4 mfma_bf16(bf16x8 a, bf16x8 b, floatx4 c) {
  return __builtin_amdgcn_mfma_f32_16x16x32_bf16(a, b, c, 0, 0, 0);
}

// async 16B global -> LDS (wave-uniform LDS base + lane*16)
__device__ __forceinline__ void async16(const void* g, void* lds) {
  __builtin_amdgcn_global_load_lds(
      (const __attribute__((address_space(1))) unsigned int*)g,
      (__attribute__((address_space(3))) unsigned int*)lds, 16, 0, 0);
}

// ---------------------------------------------------------------- weights cast
__global__ __launch_bounds__(256) void wcvt(const float* __restrict__ wq,
                                            const float* __restrict__ wp,
                                            unsigned short* __restrict__ wqb,
                                            unsigned short* __restrict__ wpb) {
  int i = blockIdx.x * 256 + threadIdx.x;
  if (i < 1152 * 384) wqb[i] = f2b(wq[i]);
  if (i < 384 * 384)  wpb[i] = f2b(wp[i]);
}

// ------------------------------------------- x (b,c,raster) fp32 -> xT[pix'][c] bf16
// block: (b, wy, wxg of 4 windows, cg of 32 channels); 2*32*8*12 = 6144 blocks
__global__ __launch_bounds__(256) void transpose_cast(const float* __restrict__ x,
                                                      unsigned short* __restrict__ xT) {
  __shared__ unsigned short sT[256 * 40];  // [pixloc][c], stride 40 (16B aligned rows)
  int id = blockIdx.x;
  int cg = id % 12; id /= 12;
  int wxg = id % 8; id /= 8;
  int wy = id % 32; id /= 32;
  int b = id;
  int tid = threadIdx.x;
  const float* xb = x + ((size_t)(b * 384 + cg * 32)) * 65536 + (size_t)(wy * 8) * 256 + wxg * 32;
#pragma unroll
  for (int it = 0; it < 8; ++it) {
    int e = it * 256 + tid;          // 0..2047: (c, y, x4)
    int c = e >> 6, rem = e & 63, y = rem >> 3, x4 = rem & 7;
    float4 v = *(const float4*)&xb[(size_t)c * 65536 + y * 256 + x4 * 4];
    int xx = x4 * 4;
    int p0 = (xx >> 3) * 64 + y * 8 + (xx & 7);   // 4 px stay in-window (no carry)
    unsigned short* dst = &sT[p0 * 40 + c];
    dst[0]   = f2b(v.x);
    dst[40]  = f2b(v.y);
    dst[80]  = f2b(v.z);
    dst[120] = f2b(v.w);
  }
  __syncthreads();
  int wl = tid >> 6, t = tid & 63;
  size_t pix = (size_t)b * 65536 + (size_t)(wy * 32 + wxg * 4 + wl) * 64 + t;
  unsigned short* dst = xT + pix * 384 + cg * 32;
  const unsigned short* src = &sT[tid * 40];
#pragma unroll
  for (int q = 0; q < 4; ++q)
    *(uint4*)(dst + q * 8) = *(const uint4*)(src + q * 8);
}

// ---------------------------------------------------------------- qkv GEMM
// C[m][n] = sum_k A[m][k]*B[n][k]; A=wqb [1152][384], B=xT [NPIX][384].
// Epilogue writes qkv2 [wing][c][t] (window-major) bf16.
__global__ __launch_bounds__(256, 4) void gemm_qkv(const unsigned short* __restrict__ A,
                                                   const unsigned short* __restrict__ B,
                                                   unsigned short* __restrict__ qkv2,
                                                   int M, int N, int K) {
  __shared__ uint4 smem4[2176];  // 34816 B: k-loop As|Bs; epilogue reuses as Cs
  unsigned short* As = (unsigned short*)smem4;            // 128*64 bf16, 16 KB
  unsigned short* Bs = (unsigned short*)smem4 + 128 * 64; // 16 KB
  const int tid = threadIdx.x;
  const int MT = M >> 7;  // 9

  // XCD-chunked bijective swizzle, M-tile fastest (B-tile shared by 9 consecutive)
  const int per = gridDim.x >> 3;
  const int vbid = (blockIdx.x & 7) * per + (blockIdx.x >> 3);
  const int Mbase = (vbid % MT) * 128;
  const int Nbase = (vbid / MT) * 128;

  const int wave = tid >> 6, lane = tid & 63;
  const int wm = wave >> 1, wn = wave & 1;
  const int l16 = lane & 15, quad = lane >> 4;
  const int Kv = K >> 3;        // row stride in uint4
  const int kTiles = K >> 6;

  // staging: linear LDS dest + pre-swizzled global source chunk
  const int lr = lane >> 3;
  const int kbs = (lane & 7) ^ lr;
  const int mrow = wave * 8 + lr;

  floatx4 acc[4][4];
#pragma unroll
  for (int mt = 0; mt < 4; ++mt)
#pragma unroll
    for (int nt = 0; nt < 4; ++nt) acc[mt][nt] = 0.f;

  const uint4* Ag = (const uint4*)(A + (size_t)Mbase * K);
  const uint4* Bg = (const uint4*)(B + (size_t)Nbase * K);

  for (int kt = 0; kt < kTiles; ++kt) {
    __syncthreads();
#pragma unroll
    for (int j = 0; j < 4; ++j) {
      int m = j * 32 + mrow;
      async16(Ag + (size_t)m * Kv + kt * 8 + kbs, (char*)As + j * 4096 + wave * 1024);
      async16(Bg + (size_t)m * Kv + kt * 8 + kbs, (char*)Bs + j * 4096 + wave * 1024);
    }
    __syncthreads();
#pragma unroll
    for (int s = 0; s < 2; ++s) {
      bf16x8 af[4], bfr[4];
#pragma unroll
      for (int mt = 0; mt < 4; ++mt) {
        int m = wm * 64 + mt * 16 + l16;
        int kk = (s * 4 + quad) ^ (m & 7);
        af[mt] = *(const bf16x8*)&As[(m * 8 + kk) * 8];
      }
#pragma unroll
      for (int nt = 0; nt < 4; ++nt) {
        int n = wn * 64 + nt * 16 + l16;
        int kk = (s * 4 + quad) ^ (n & 7);
        bfr[nt] = *(const bf16x8*)&Bs[(n * 8 + kk) * 8];
      }
#pragma unroll
      for (int mt = 0; mt < 4; ++mt)
#pragma unroll
        for (int nt = 0; nt < 4; ++nt)
          acc[mt][nt] = mfma_bf16(af[mt], bfr[nt], acc[mt][nt]);
    }
  }

  // epilogue: stage in LDS, write [wing][c][t] (8x128B segments per wave-instr)
  unsigned short* Cs = (unsigned short*)smem4;  // [128][136]
  __syncthreads();
#pragma unroll
  for (int mt = 0; mt < 4; ++mt)
#pragma unroll
    for (int nt = 0; nt < 4; ++nt)
#pragma unroll
      for (int r = 0; r < 4; ++r) {
        int lm = wm * 64 + mt * 16 + quad * 4 + r;
        int ln = wn * 64 + nt * 16 + l16;
        Cs[lm * 136 + ln] = f2b(acc[mt][nt][r]);
      }
  __syncthreads();
  const int wing0 = Nbase >> 6;  // 128-px tile = 2 windows
#pragma unroll
  for (int it = 0; it < 8; ++it) {
    int slot = it * 256 + tid;
    int row = slot >> 4, ch = slot & 15;
    unsigned short* dst = qkv2 + (size_t)(wing0 + (ch >> 3)) * 73728 +
                          (size_t)(Mbase + row) * 64 + (ch & 7) * 8;
    *(uint4*)dst = *(const uint4*)&Cs[row * 136 + ch * 8];
  }
}

// ---------------------------------------------------------------- fused attn+proj
// block = one window (2048 blocks), 256 threads (4 waves, wave w owns t in [16w,16w+16)).
// Per head: QK^T -> softmax -> PV -> O into sAOT[t][h*48+d]; then proj GEMM
// out[o][t] = sum_c wp[o][c] * aoT[t][c] with wp streamed from L2.
__global__ __launch_bounds__(256, 2) void attnproj(const unsigned short* __restrict__ qkv2,
                                                   const unsigned short* __restrict__ wpb,
                                                   float* __restrict__ out) {
  __shared__ unsigned short sAOT[64 * 392];  // [t][c], stride 392 (2-way bank = free)
  __shared__ unsigned short sQ[64 * 72];     // [t][d] d-pad to 64; aliased as sP
  __shared__ unsigned short sK[64 * 72];     // [u][d]; pad cols zeroed once
  __shared__ unsigned short sV[48 * 72];     // [d][u]

  const int bid = blockIdx.x;
  const int wing = (bid & 7) * 256 + (bid >> 3);  // window pairs share one XCD L2
  const int b = wing >> 10, win = wing & 1023;
  const int hh0 = (win >> 5) * 8, ww0 = (win & 31) * 8;
  const int tid = threadIdx.x;
  const unsigned short* base = qkv2 + (size_t)wing * 73728;

  const int wave = tid >> 6, lane = tid & 63;
  const int l16 = lane & 15, quad = lane >> 4;
  const int tb = wave * 16;

  // zero Q and K pad cols 48..63 once.  (Q pad MUST be zeroed too: uninitialized
  // LDS can decode as bf16 Inf/NaN, and Inf*0 = NaN inside the MFMA -- the pad
  // product is only harmless if both sides are finite.)
  if (tid < 64) {
    const uint4 z = {0u, 0u, 0u, 0u};
    *(uint4*)&sK[tid * 72 + 48] = z;
    *(uint4*)&sK[tid * 72 + 56] = z;
    *(uint4*)&sQ[tid * 72 + 48] = z;
    *(uint4*)&sQ[tid * 72 + 56] = z;
  }

  // per-thread load tasks: Q/K = 768 tasks (48 d x 8 groups of 8 t), V = 384 uint4 rows
  int qd[3], qg[3], qko[3];
#pragma unroll
  for (int j = 0; j < 3; ++j) {
    int task = j * 256 + tid;
    int isK = task >= 384;
    int r = task - (isK ? 384 : 0);
    qd[j] = r >> 3; qg[j] = r & 7; qko[j] = isK ? 24576 : 0;
  }
  const int vd0 = tid >> 3, vc8 = tid & 7;

  // prefetch head 0 into regs (T14: global->reg early, LDS-write late)
  uint4 vqk[3], vv0, vv1;
#pragma unroll
  for (int j = 0; j < 3; ++j)
    vqk[j] = *(const uint4*)(base + qko[j] + qd[j] * 64 + qg[j] * 8);
  vv0 = *(const uint4*)(base + 49152 + vd0 * 64 + vc8 * 8);
  if (tid < 128) vv1 = *(const uint4*)(base + 49152 + (32 + vd0) * 64 + vc8 * 8);

#pragma unroll
  for (int h = 0; h < 8; ++h) {
    __syncthreads();  // all waves done reading sQ/sK/sV of previous head
    // commit staged regs: Q,K transposed ([t][d]) via scalar unpack, V rows direct
#pragma unroll
    for (int j = 0; j < 3; ++j) {
      unsigned short* dst = (qko[j] ? sK : sQ) + (qg[j] * 8) * 72 + qd[j];
      uint4 v = vqk[j];
      dst[0]   = (unsigned short)(v.x);
      dst[72]  = (unsigned short)(v.x >> 16);
      dst[144] = (unsigned short)(v.y);
      dst[216] = (unsigned short)(v.y >> 16);
      dst[288] = (unsigned short)(v.z);
      dst[360] = (unsigned short)(v.z >> 16);
      dst[432] = (unsigned short)(v.w);
      dst[504] = (unsigned short)(v.w >> 16);
    }
    *(uint4*)&sV[vd0 * 72 + vc8 * 8] = vv0;
    if (tid < 128) *(uint4*)&sV[(32 + vd0) * 72 + vc8 * 8] = vv1;
    // prefetch head h+1 (lands under this head's compute)
    if (h < 7) {
      int hb = (h + 1) * 48;
#pragma unroll
      for (int j = 0; j < 3; ++j)
        vqk[j] = *(const uint4*)(base + qko[j] + (hb + qd[j]) * 64 + qg[j] * 8);
      vv0 = *(const uint4*)(base + 49152 + (hb + vd0) * 64 + vc8 * 8);
      if (tid < 128) vv1 = *(const uint4*)(base + 49152 + (hb + 32 + vd0) * 64 + vc8 * 8);
    }
    __syncthreads();

    // S = Q K^T (k-dim = d padded to 64)
    floatx4 sacc[4];
#pragma unroll
    for (int nt = 0; nt < 4; ++nt) sacc[nt] = 0.f;
#pragma unroll
    for (int s = 0; s < 2; ++s) {
      bf16x8 aq = *(const bf16x8*)&sQ[(tb + l16) * 72 + s * 32 + quad * 8];
#pragma unroll
      for (int nt = 0; nt < 4; ++nt) {
        bf16x8 bk = *(const bf16x8*)&sK[(nt * 16 + l16) * 72 + s * 32 + quad * 8];
        sacc[nt] = mfma_bf16(aq, bk, sacc[nt]);
      }
    }
    // softmax over u; write P into sP (= sQ alias; each wave touches only its 16 rows)
    unsigned short* sP = sQ;
#pragma unroll
    for (int r = 0; r < 4; ++r) {
      float v0 = sacc[0][r] * SCALE, v1 = sacc[1][r] * SCALE;
      float v2 = sacc[2][r] * SCALE, v3 = sacc[3][r] * SCALE;
      float mx = fmaxf(fmaxf(v0, v1), fmaxf(v2, v3));
      mx = fmaxf(mx, __shfl_xor(mx, 1));
      mx = fmaxf(mx, __shfl_xor(mx, 2));
      mx = fmaxf(mx, __shfl_xor(mx, 4));
      mx = fmaxf(mx, __shfl_xor(mx, 8));
      float p0 = __expf(v0 - mx), p1 = __expf(v1 - mx);
      float p2 = __expf(v2 - mx), p3 = __expf(v3 - mx);
      float sum = p0 + p1 + p2 + p3;
      sum += __shfl_xor(sum, 1);
      sum += __shfl_xor(sum, 2);
      sum += __shfl_xor(sum, 4);
      sum += __shfl_xor(sum, 8);
      float inv = 1.f / sum;
      int t = tb + quad * 4 + r;
      sP[t * 72 + 0 * 16 + l16] = f2b(p0 * inv);
      sP[t * 72 + 1 * 16 + l16] = f2b(p1 * inv);
      sP[t * 72 + 2 * 16 + l16] = f2b(p2 * inv);
      sP[t * 72 + 3 * 16 + l16] = f2b(p3 * inv);
    }
    // O = P V (no barrier needed: wave reads only its own P rows)
    floatx4 oacc[3];
#pragma unroll
    for (int nt = 0; nt < 3; ++nt) oacc[nt] = 0.f;
#pragma unroll
    for (int s = 0; s < 2; ++s) {
      bf16x8 ap = *(const bf16x8*)&sP[(tb + l16) * 72 + s * 32 + quad * 8];
#pragma unroll
      for (int nt = 0; nt < 3; ++nt) {
        bf16x8 bv = *(const bf16x8*)&sV[(nt * 16 + l16) * 72 + s * 32 + quad * 8];
        oacc[nt] = mfma_bf16(ap, bv, oacc[nt]);
      }
    }
#pragma unroll
    for (int nt = 0; nt < 3; ++nt)
#pragma unroll
      for (int r = 0; r < 4; ++r) {
        int t = tb + quad * 4 + r, d = nt * 16 + l16;
        sAOT[t * 392 + h * 48 + d] = f2b(oacc[nt][r]);
      }
  }

  __syncthreads();  // sAOT complete

  // proj: C[o=384][t=64], wave owns o in [96w, 96w+96): 6 Mtiles x 4 Ntiles, K=384
  floatx4 pacc[6][4];
#pragma unroll
  for (int mt = 0; mt < 6; ++mt)
#pragma unroll
    for (int nt = 0; nt < 4; ++nt) pacc[mt][nt] = 0.f;
  const int o0 = wave * 96;
#pragma unroll
  for (int kc = 0; kc < 12; ++kc) {
    bf16x8 bfp[4];
#pragma unroll
    for (int nt = 0; nt < 4; ++nt)
      bfp[nt] = *(const bf16x8*)&sAOT[(nt * 16 + l16) * 392 + kc * 32 + quad * 8];
#pragma unroll
    for (int mt = 0; mt < 6; ++mt) {
      bf16x8 af = *(const bf16x8*)&wpb[(size_t)(o0 + mt * 16 + l16) * 384 + kc * 32 + quad * 8];
#pragma unroll
      for (int nt = 0; nt < 4; ++nt)
        pacc[mt][nt] = mfma_bf16(af, bfp[nt], pacc[mt][nt]);
    }
  }
  // scatter: per (o,ty) 8 contiguous floats (32B); pair-window L2 merge via XCD swizzle
  float* outb = out + (size_t)b * 384 * 65536 + (size_t)hh0 * 256 + ww0;
#pragma unroll
  for (int mt = 0; mt < 6; ++mt)
#pragma unroll
    for (int nt = 0; nt < 4; ++nt)
#pragma unroll
      for (int r = 0; r < 4; ++r) {
        int o = o0 + mt * 16 + quad * 4 + r;
        int t = nt * 16 + l16;
        outb[(size_t)o * 65536 + (t >> 3) * 256 + (t & 7)] = pacc[mt][nt][r];
      }
}

// ---------------------------------------------------------------- launch
extern "C" void kernel_launch(void* const* d_in, const int* in_sizes, int n_in,
                              void* d_out, int out_size, void* d_ws, size_t ws_size,
                              hipStream_t stream) {
  const float* x  = (const float*)d_in[0];
  const float* wq = (const float*)d_in[1];
  const float* wp = (const float*)d_in[2];
  float* out = (float*)d_out;

  char* ws = (char*)d_ws;
  // workspace layout (bytes): ~403.8 MB
  unsigned short* xT   = (unsigned short*)(ws);                 // 100,663,296
  unsigned short* qkv2 = (unsigned short*)(ws + 100663296ull);  // 301,989,888
  unsigned short* wqb  = (unsigned short*)(ws + 402653184ull);  //     884,736
  unsigned short* wpb  = (unsigned short*)(ws + 403537920ull);  //     294,912

  wcvt<<<1728, 256, 0, stream>>>(wq, wp, wqb, wpb);
  transpose_cast<<<6144, 256, 0, stream>>>(x, xT);
  gemm_qkv<<<9216, 256, 0, stream>>>(wqb, xT, qkv2, 1152, NPIX, KDIM);
  attnproj<<<2048, 256, 0, stream>>>(qkv2, wpb, out);
}

// Round 6
// 698.955 us; speedup vs baseline: 1.0587x; 1.0186x over previous
//
#include <hip/hip_runtime.h>

// Shapes (hardcoded): x (2,384,256,256) fp32, w_qkv (1152,384), w_proj (384,384).
// out (2,384,256,256) fp32.  WS=8, NH=8, HD=48.  256%8==0 -> no reflect pad.
// wing = b*1024 + wy*32 + wx  (global window id, 2048 total), t = ty*8+tx.
// qkv2 layout: [wing][c=1152][t=64] bf16 (per-window contiguous 147 KB slice).

#define NPIX 131072   // 2*256*256
#define KDIM 384
#define SCALE 0.14433756729740643f  // 48^-0.5

typedef __attribute__((ext_vector_type(8))) short bf16x8;   // 8 bf16 in 4 VGPRs
typedef __attribute__((ext_vector_type(4))) float floatx4;

__device__ __forceinline__ unsigned short f2b(float f) {
  union { float f; unsigned u; } v; v.f = f;
  return (unsigned short)((v.u + 0x7FFFu + ((v.u >> 16) & 1u)) >> 16);  // RNE
}

__device__ __forceinline__ floatx4 mfma_bf16(bf16x8 a, bf16x8 b, floatx4 c) {
  return __builtin_amdgcn_mfma_f32_16x16x32_bf16(a, b, c, 0, 0, 0);
}

// async 16B global -> LDS (wave-uniform LDS base + lane*16)
__device__ __forceinline__ void async16(const void* g, void* lds) {
  __builtin_amdgcn_global_load_lds(
      (const __attribute__((address_space(1))) unsigned int*)g,
      (__attribute__((address_space(3))) unsigned int*)lds, 16, 0, 0);
}

// ---------------------------------------------------------------- weights cast
__global__ __launch_bounds__(256) void wcvt(const float* __restrict__ wq,
                                            const float* __restrict__ wp,
                                            unsigned short* __restrict__ wqb,
                                            unsigned short* __restrict__ wpb) {
  int i = blockIdx.x * 256 + threadIdx.x;
  if (i < 1152 * 384) wqb[i] = f2b(wq[i]);
  if (i < 384 * 384)  wpb[i] = f2b(wp[i]);
}

// ------------------------------------------- x (b,c,raster) fp32 -> xT[pix'][c] bf16
// block: (b, wy, wxg of 4 windows, cg of 32 channels); 2*32*8*12 = 6144 blocks
// Channel-PAIR u32 LDS stores + 16B chunk swizzle by (p0>>2): breaks the 32-way
// bank conflict of the scalar-u16 version (8-px row stride 640B == 0 mod 128B).
__global__ __launch_bounds__(256) void transpose_cast(const float* __restrict__ x,
                                                      unsigned short* __restrict__ xT) {
  __shared__ unsigned short sT[256 * 40];  // [pixloc][c-swizzled], stride 40
  int id = blockIdx.x;
  int cg = id % 12; id /= 12;
  int wxg = id % 8; id /= 8;
  int wy = id % 32; id /= 32;
  int b = id;
  int tid = threadIdx.x;
  const float* xb = x + ((size_t)(b * 384 + cg * 32)) * 65536 + (size_t)(wy * 8) * 256 + wxg * 32;
#pragma unroll
  for (int it = 0; it < 4; ++it) {
    int task = it * 256 + tid;             // 1024 tasks: (y 8) x (cpair 16) x (x4 8)
    int x4 = task & 7, cp = (task >> 3) & 15, y = task >> 7;
    const float* p = &xb[(size_t)(cp * 2) * 65536 + y * 256 + x4 * 4];
    float4 v0 = *(const float4*)p;            // channel 2cp, 4 px
    float4 v1 = *(const float4*)(p + 65536);  // channel 2cp+1
    int xx = x4 * 4;
    int p0 = (xx >> 3) * 64 + y * 8 + (xx & 7);   // 4 px contiguous in pixloc
    // physical pair slot: keep cp&3 in place, swizzle 16B chunk by p0>>2
    int col = ((cp & 3) + ((((cp >> 2) ^ (p0 >> 2)) & 3) << 2)) * 2;
    unsigned w0 = (unsigned)f2b(v0.x) | ((unsigned)f2b(v1.x) << 16);
    unsigned w1 = (unsigned)f2b(v0.y) | ((unsigned)f2b(v1.y) << 16);
    unsigned w2 = (unsigned)f2b(v0.z) | ((unsigned)f2b(v1.z) << 16);
    unsigned w3 = (unsigned)f2b(v0.w) | ((unsigned)f2b(v1.w) << 16);
    *(unsigned*)&sT[(p0 + 0) * 40 + col] = w0;
    *(unsigned*)&sT[(p0 + 1) * 40 + col] = w1;
    *(unsigned*)&sT[(p0 + 2) * 40 + col] = w2;
    *(unsigned*)&sT[(p0 + 3) * 40 + col] = w3;
  }
  __syncthreads();
  int wl = tid >> 6, t = tid & 63;
  size_t pix = (size_t)b * 65536 + (size_t)(wy * 32 + wxg * 4 + wl) * 64 + t;
  unsigned short* dst = xT + pix * 384 + cg * 32;
  const unsigned short* src = &sT[tid * 40];
  const int psw = (tid >> 2) & 3;
#pragma unroll
  for (int q = 0; q < 4; ++q)
    *(uint4*)(dst + q * 8) = *(const uint4*)(src + ((q ^ psw) << 3));
}

// ---------------------------------------------------------------- qkv GEMM
// C[m][n] = sum_k A[m][k]*B[n][k]; A=wqb [1152][384], B=xT [NPIX][384].
// Epilogue writes qkv2 [wing][c][t] (window-major) bf16.
__global__ __launch_bounds__(256, 4) void gemm_qkv(const unsigned short* __restrict__ A,
                                                   const unsigned short* __restrict__ B,
                                                   unsigned short* __restrict__ qkv2,
                                                   int M, int N, int K) {
  __shared__ uint4 smem4[2176];  // 34816 B: k-loop As|Bs; epilogue reuses as Cs
  unsigned short* As = (unsigned short*)smem4;            // 128*64 bf16, 16 KB
  unsigned short* Bs = (unsigned short*)smem4 + 128 * 64; // 16 KB
  const int tid = threadIdx.x;
  const int MT = M >> 7;  // 9

  // XCD-chunked bijective swizzle, M-tile fastest (B-tile shared by 9 consecutive)
  const int per = gridDim.x >> 3;
  const int vbid = (blockIdx.x & 7) * per + (blockIdx.x >> 3);
  const int Mbase = (vbid % MT) * 128;
  const int Nbase = (vbid / MT) * 128;

  const int wave = tid >> 6, lane = tid & 63;
  const int wm = wave >> 1, wn = wave & 1;
  const int l16 = lane & 15, quad = lane >> 4;
  const int Kv = K >> 3;        // row stride in uint4
  const int kTiles = K >> 6;

  // staging: linear LDS dest + pre-swizzled global source chunk
  const int lr = lane >> 3;
  const int kbs = (lane & 7) ^ lr;
  const int mrow = wave * 8 + lr;

  floatx4 acc[4][4];
#pragma unroll
  for (int mt = 0; mt < 4; ++mt)
#pragma unroll
    for (int nt = 0; nt < 4; ++nt) acc[mt][nt] = 0.f;

  const uint4* Ag = (const uint4*)(A + (size_t)Mbase * K);
  const uint4* Bg = (const uint4*)(B + (size_t)Nbase * K);

  for (int kt = 0; kt < kTiles; ++kt) {
    __syncthreads();
#pragma unroll
    for (int j = 0; j < 4; ++j) {
      int m = j * 32 + mrow;
      async16(Ag + (size_t)m * Kv + kt * 8 + kbs, (char*)As + j * 4096 + wave * 1024);
      async16(Bg + (size_t)m * Kv + kt * 8 + kbs, (char*)Bs + j * 4096 + wave * 1024);
    }
    __syncthreads();
#pragma unroll
    for (int s = 0; s < 2; ++s) {
      bf16x8 af[4], bfr[4];
#pragma unroll
      for (int mt = 0; mt < 4; ++mt) {
        int m = wm * 64 + mt * 16 + l16;
        int kk = (s * 4 + quad) ^ (m & 7);
        af[mt] = *(const bf16x8*)&As[(m * 8 + kk) * 8];
      }
#pragma unroll
      for (int nt = 0; nt < 4; ++nt) {
        int n = wn * 64 + nt * 16 + l16;
        int kk = (s * 4 + quad) ^ (n & 7);
        bfr[nt] = *(const bf16x8*)&Bs[(n * 8 + kk) * 8];
      }
#pragma unroll
      for (int mt = 0; mt < 4; ++mt)
#pragma unroll
        for (int nt = 0; nt < 4; ++nt)
          acc[mt][nt] = mfma_bf16(af[mt], bfr[nt], acc[mt][nt]);
    }
  }

  // epilogue: stage in LDS, write [wing][c][t] (8x128B segments per wave-instr)
  unsigned short* Cs = (unsigned short*)smem4;  // [128][136]
  __syncthreads();
#pragma unroll
  for (int mt = 0; mt < 4; ++mt)
#pragma unroll
    for (int nt = 0; nt < 4; ++nt)
#pragma unroll
      for (int r = 0; r < 4; ++r) {
        int lm = wm * 64 + mt * 16 + quad * 4 + r;
        int ln = wn * 64 + nt * 16 + l16;
        Cs[lm * 136 + ln] = f2b(acc[mt][nt][r]);
      }
  __syncthreads();
  const int wing0 = Nbase >> 6;  // 128-px tile = 2 windows
#pragma unroll
  for (int it = 0; it < 8; ++it) {
    int slot = it * 256 + tid;
    int row = slot >> 4, ch = slot & 15;
    unsigned short* dst = qkv2 + (size_t)(wing0 + (ch >> 3)) * 73728 +
                          (size_t)(Mbase + row) * 64 + (ch & 7) * 8;
    *(uint4*)dst = *(const uint4*)&Cs[row * 136 + ch * 8];
  }
}

// ---------------------------------------------------------------- fused attn+proj
// block = one window (2048 blocks), 256 threads (4 waves, wave w owns t in [16w,16w+16)).
// sQ/sK use a 16B chunk XOR-swizzle by row-group g=(t>>3)&7: logical chunk ck at
// physical (ck^g).  This makes the transposed Q/K unpack writes conflict-free
// (was 16-way: 8 rows x 144B stride == 0 mod 128B wiped the g-term from banks).
__global__ __launch_bounds__(256, 2) void attnproj(const unsigned short* __restrict__ qkv2,
                                                   const unsigned short* __restrict__ wpb,
                                                   float* __restrict__ out) {
  __shared__ unsigned short sAOT[64 * 392];  // [t][c], stride 392
  __shared__ unsigned short sQ[64 * 72];     // [t][d-pad-64], chunk-swizzled; alias sP
  __shared__ unsigned short sK[64 * 72];     // [u][d-pad-64], chunk-swizzled
  __shared__ unsigned short sV[48 * 72];     // [d][u]

  const int bid = blockIdx.x;
  const int wing = (bid & 7) * 256 + (bid >> 3);  // window pairs share one XCD L2
  const int b = wing >> 10, win = wing & 1023;
  const int hh0 = (win >> 5) * 8, ww0 = (win & 31) * 8;
  const int tid = threadIdx.x;
  const unsigned short* base = qkv2 + (size_t)wing * 73728;

  const int wave = tid >> 6, lane = tid & 63;
  const int l16 = lane & 15, quad = lane >> 4;
  const int tb = wave * 16;

  // zero Q and K pad (logical chunks 6,7 -> physical (6^g),(7^g)).  Q pad must be
  // finite too: uninitialized LDS can decode as bf16 Inf/NaN and Inf*0=NaN in MFMA.
  if (tid < 64) {
    int g = (tid >> 3) & 7;
    const uint4 z = {0u, 0u, 0u, 0u};
    *(uint4*)&sK[tid * 72 + ((6 ^ g) << 3)] = z;
    *(uint4*)&sK[tid * 72 + ((7 ^ g) << 3)] = z;
    *(uint4*)&sQ[tid * 72 + ((6 ^ g) << 3)] = z;
    *(uint4*)&sQ[tid * 72 + ((7 ^ g) << 3)] = z;
  }

  // per-thread load tasks: Q/K = 768 tasks (48 d x 8 groups of 8 t), V = 384 uint4 rows
  int qd[3], qg[3], qko[3];
#pragma unroll
  for (int j = 0; j < 3; ++j) {
    int task = j * 256 + tid;
    int isK = task >= 384;
    int r = task - (isK ? 384 : 0);
    qd[j] = r >> 3; qg[j] = r & 7; qko[j] = isK ? 24576 : 0;
  }
  const int vd0 = tid >> 3, vc8 = tid & 7;

  // prefetch head 0 into regs (T14: global->reg early, LDS-write late)
  uint4 vqk[3], vv0, vv1;
#pragma unroll
  for (int j = 0; j < 3; ++j)
    vqk[j] = *(const uint4*)(base + qko[j] + qd[j] * 64 + qg[j] * 8);
  vv0 = *(const uint4*)(base + 49152 + vd0 * 64 + vc8 * 8);
  if (tid < 128) vv1 = *(const uint4*)(base + 49152 + (32 + vd0) * 64 + vc8 * 8);

#pragma unroll
  for (int h = 0; h < 8; ++h) {
    __syncthreads();  // all waves done reading sQ/sK/sV of previous head
    // commit staged regs: Q,K transposed ([t][d]) via scalar unpack into swizzled
    // chunks: lane's col = (qd&7) + 8*((qd>>3)^qg); rows t = qg*8 + i.
    // Banks per store: 4i + 4*((qd>>3)^qg) + ((lane>>3)>>1) -> 2 lanes/bank (free).
#pragma unroll
    for (int j = 0; j < 3; ++j) {
      unsigned short* dst = (qko[j] ? sK : sQ) + (qg[j] * 8) * 72 +
                            (qd[j] & 7) + ((((qd[j] >> 3) ^ qg[j]) & 7) << 3);
      uint4 v = vqk[j];
      dst[0]   = (unsigned short)(v.x);
      dst[72]  = (unsigned short)(v.x >> 16);
      dst[144] = (unsigned short)(v.y);
      dst[216] = (unsigned short)(v.y >> 16);
      dst[288] = (unsigned short)(v.z);
      dst[360] = (unsigned short)(v.z >> 16);
      dst[432] = (unsigned short)(v.w);
      dst[504] = (unsigned short)(v.w >> 16);
    }
    *(uint4*)&sV[vd0 * 72 + vc8 * 8] = vv0;
    if (tid < 128) *(uint4*)&sV[(32 + vd0) * 72 + vc8 * 8] = vv1;
    // prefetch head h+1 (lands under this head's compute)
    if (h < 7) {
      int hb = (h + 1) * 48;
#pragma unroll
      for (int j = 0; j < 3; ++j)
        vqk[j] = *(const uint4*)(base + qko[j] + (hb + qd[j]) * 64 + qg[j] * 8);
      vv0 = *(const uint4*)(base + 49152 + (hb + vd0) * 64 + vc8 * 8);
      if (tid < 128) vv1 = *(const uint4*)(base + 49152 + (hb + 32 + vd0) * 64 + vc8 * 8);
    }
    __syncthreads();

    // S = Q K^T (k-dim = d padded to 64); fragment chunk = (s*4+quad) ^ row-group
    floatx4 sacc[4];
#pragma unroll
    for (int nt = 0; nt < 4; ++nt) sacc[nt] = 0.f;
    const int rq = tb + l16, gq = (rq >> 3) & 7;
#pragma unroll
    for (int s = 0; s < 2; ++s) {
      bf16x8 aq = *(const bf16x8*)&sQ[rq * 72 + (((s * 4 + quad) ^ gq) << 3)];
#pragma unroll
      for (int nt = 0; nt < 4; ++nt) {
        int rk = nt * 16 + l16, gk = (rk >> 3) & 7;
        bf16x8 bk = *(const bf16x8*)&sK[rk * 72 + (((s * 4 + quad) ^ gk) << 3)];
        sacc[nt] = mfma_bf16(aq, bk, sacc[nt]);
      }
    }
    // softmax over u; write P into sP (= sQ alias; wave touches only its 16 rows),
    // same logical->physical chunk swizzle.
    unsigned short* sP = sQ;
#pragma unroll
    for (int r = 0; r < 4; ++r) {
      float v0 = sacc[0][r] * SCALE, v1 = sacc[1][r] * SCALE;
      float v2 = sacc[2][r] * SCALE, v3 = sacc[3][r] * SCALE;
      float mx = fmaxf(fmaxf(v0, v1), fmaxf(v2, v3));
      mx = fmaxf(mx, __shfl_xor(mx, 1));
      mx = fmaxf(mx, __shfl_xor(mx, 2));
      mx = fmaxf(mx, __shfl_xor(mx, 4));
      mx = fmaxf(mx, __shfl_xor(mx, 8));
      float p0 = __expf(v0 - mx), p1 = __expf(v1 - mx);
      float p2 = __expf(v2 - mx), p3 = __expf(v3 - mx);
      float sum = p0 + p1 + p2 + p3;
      sum += __shfl_xor(sum, 1);
      sum += __shfl_xor(sum, 2);
      sum += __shfl_xor(sum, 4);
      sum += __shfl_xor(sum, 8);
      float inv = 1.f / sum;
      int t = tb + quad * 4 + r;
      int gt = (t >> 3) & 7;
      int bch = l16 >> 3, wl = l16 & 7;
      sP[t * 72 + (((0 + bch) ^ gt) << 3) + wl] = f2b(p0 * inv);
      sP[t * 72 + (((2 + bch) ^ gt) << 3) + wl] = f2b(p1 * inv);
      sP[t * 72 + (((4 + bch) ^ gt) << 3) + wl] = f2b(p2 * inv);
      sP[t * 72 + (((6 + bch) ^ gt) << 3) + wl] = f2b(p3 * inv);
    }
    // O = P V (no barrier needed: wave reads only its own P rows)
    floatx4 oacc[3];
#pragma unroll
    for (int nt = 0; nt < 3; ++nt) oacc[nt] = 0.f;
#pragma unroll
    for (int s = 0; s < 2; ++s) {
      bf16x8 ap = *(const bf16x8*)&sP[rq * 72 + (((s * 4 + quad) ^ gq) << 3)];
#pragma unroll
      for (int nt = 0; nt < 3; ++nt) {
        bf16x8 bv = *(const bf16x8*)&sV[(nt * 16 + l16) * 72 + s * 32 + quad * 8];
        oacc[nt] = mfma_bf16(ap, bv, oacc[nt]);
      }
    }
#pragma unroll
    for (int nt = 0; nt < 3; ++nt)
#pragma unroll
      for (int r = 0; r < 4; ++r) {
        int t = tb + quad * 4 + r, d = nt * 16 + l16;
        sAOT[t * 392 + h * 48 + d] = f2b(oacc[nt][r]);
      }
  }

  __syncthreads();  // sAOT complete

  // proj: C[o=384][t=64], wave owns o in [96w, 96w+96): 6 Mtiles x 4 Ntiles, K=384
  floatx4 pacc[6][4];
#pragma unroll
  for (int mt = 0; mt < 6; ++mt)
#pragma unroll
    for (int nt = 0; nt < 4; ++nt) pacc[mt][nt] = 0.f;
  const int o0 = wave * 96;
#pragma unroll
  for (int kc = 0; kc < 12; ++kc) {
    bf16x8 bfp[4];
#pragma unroll
    for (int nt = 0; nt < 4; ++nt)
      bfp[nt] = *(const bf16x8*)&sAOT[(nt * 16 + l16) * 392 + kc * 32 + quad * 8];
#pragma unroll
    for (int mt = 0; mt < 6; ++mt) {
      bf16x8 af = *(const bf16x8*)&wpb[(size_t)(o0 + mt * 16 + l16) * 384 + kc * 32 + quad * 8];
#pragma unroll
      for (int nt = 0; nt < 4; ++nt)
        pacc[mt][nt] = mfma_bf16(af, bfp[nt], pacc[mt][nt]);
    }
  }
  // scatter: per (o,ty) 8 contiguous floats (32B); pair-window L2 merge via XCD swizzle
  float* outb = out + (size_t)b * 384 * 65536 + (size_t)hh0 * 256 + ww0;
#pragma unroll
  for (int mt = 0; mt < 6; ++mt)
#pragma unroll
    for (int nt = 0; nt < 4; ++nt)
#pragma unroll
      for (int r = 0; r < 4; ++r) {
        int o = o0 + mt * 16 + quad * 4 + r;
        int t = nt * 16 + l16;
        outb[(size_t)o * 65536 + (t >> 3) * 256 + (t & 7)] = pacc[mt][nt][r];
      }
}

// ---------------------------------------------------------------- launch
extern "C" void kernel_launch(void* const* d_in, const int* in_sizes, int n_in,
                              void* d_out, int out_size, void* d_ws, size_t ws_size,
                              hipStream_t stream) {
  const float* x  = (const float*)d_in[0];
  const float* wq = (const float*)d_in[1];
  const float* wp = (const float*)d_in[2];
  float* out = (float*)d_out;

  char* ws = (char*)d_ws;
  // workspace layout (bytes): ~403.8 MB
  unsigned short* xT   = (unsigned short*)(ws);                 // 100,663,296
  unsigned short* qkv2 = (unsigned short*)(ws + 100663296ull);  // 301,989,888
  unsigned short* wqb  = (unsigned short*)(ws + 402653184ull);  //     884,736
  unsigned short* wpb  = (unsigned short*)(ws + 403537920ull);  //     294,912

  wcvt<<<1728, 256, 0, stream>>>(wq, wp, wqb, wpb);
  transpose_cast<<<6144, 256, 0, stream>>>(x, xT);
  gemm_qkv<<<9216, 256, 0, stream>>>(wqb, xT, qkv2, 1152, NPIX, KDIM);
  attnproj<<<2048, 256, 0, stream>>>(qkv2, wpb, out);
}